// Round 18
// baseline (783.309 us; speedup 1.0000x reference)
//
#include <hip/hip_runtime.h>
#include <hip/hip_bf16.h>
#include <math.h>

// ---------- types ----------
typedef __attribute__((ext_vector_type(8))) short          bf16x8;
typedef __attribute__((ext_vector_type(8))) unsigned short ushort8;
typedef __attribute__((ext_vector_type(4))) float          f32x4;

__device__ __forceinline__ unsigned short f2bf(float f) {
    union { float f; unsigned u; } v; v.f = f;
    unsigned u = v.u;
    unsigned r = (u + 0x7FFFu + ((u >> 16) & 1u)) >> 16;   // RNE
    return (unsigned short)r;
}
__device__ __forceinline__ float bf2f(unsigned short h) {
    union { unsigned u; float f; } v; v.u = ((unsigned)h) << 16;
    return v.f;
}

// async global->LDS, 16B per lane (m97 pattern)
__device__ __forceinline__ void gload16(const void* g, void* l) {
    __builtin_amdgcn_global_load_lds(
        (const __attribute__((address_space(1))) void*)g,
        (__attribute__((address_space(3))) void*)l, 16, 0, 0);
}

// XCD-aware bijective block remap (requires nwg % 8 == 0)
__device__ __forceinline__ int xcd_swz(int bid, int nwg) {
    return (bid & 7) * (nwg >> 3) + (bid >> 3);
}

// ---------- weight transpose-cast: in[K][N] f32 -> out[N][K] bf16 ----------
__global__ __launch_bounds__(256) void wt_cast_k(const float* __restrict__ in,
                                                 unsigned short* __restrict__ out,
                                                 int K, int N) {
    __shared__ float t[64][65];
    in  += (size_t)blockIdx.z * K * N;
    out += (size_t)blockIdx.z * K * N;
    int n0 = blockIdx.x * 64, k0 = blockIdx.y * 64;
    int tx = threadIdx.x & 63, ty = threadIdx.x >> 6;
    #pragma unroll
    for (int p = 0; p < 16; ++p) {
        int k = ty + p * 4;
        t[k][tx] = in[(size_t)(k0 + k) * N + n0 + tx];
    }
    __syncthreads();
    #pragma unroll
    for (int p = 0; p < 16; ++p) {
        int n = ty + p * 4;
        out[(size_t)(n0 + n) * K + k0 + tx] = f2bf(t[tx][n]);
    }
}

// ---------- cos/sin table for RoPE: [1024][16] ----------
__global__ __launch_bounds__(256) void cossin_k(const float* __restrict__ inv_freq,
                                                float* __restrict__ cosT,
                                                float* __restrict__ sinT) {
    int idx = blockIdx.x * 256 + threadIdx.x;     // 16384
    int t = idx >> 4, p = idx & 15;
    float fr = (float)t * inv_freq[p];
    cosT[idx] = cosf(fr);
    sinT[idx] = sinf(fr);
}

// ---------- mask triviality flags ----------
__global__ __launch_bounds__(256) void mask_flags_k(const float* __restrict__ mask,
                                                    unsigned char* __restrict__ flags) {
    int idx = blockIdx.x;                    // (bh*16 + qt)*16 + kt
    int tid = threadIdx.x;
    int kt = idx & 15, qt = (idx >> 4) & 15, bh = idx >> 8;
    int r = tid >> 2, cc = (tid & 3) * 16;
    const float* prow = mask + ((size_t)bh * 1024 + (size_t)qt * 64 + r) * 1024 + kt * 64 + cc;
    int bad = 0;
    #pragma unroll
    for (int j = 0; j < 4; ++j) {
        float4 v = *(const float4*)(prow + j * 4);
        bad |= (v.x != 1.f) || (v.y != 1.f) || (v.z != 1.f) || (v.w != 1.f);
    }
    __shared__ int sb[4];
    unsigned long long anyb = __ballot(bad != 0);
    if ((tid & 63) == 0) sb[tid >> 6] = (anyb != 0ull) ? 1 : 0;
    __syncthreads();
    if (tid == 0) flags[idx] = (unsigned char)(!(sb[0] | sb[1] | sb[2] | sb[3]));
}

// ---------- LayerNorm 768, f32 in -> bf16 out ----------
__global__ __launch_bounds__(256) void ln768_bf_k(const float* __restrict__ in,
                                                  const float* __restrict__ g,
                                                  const float* __restrict__ b,
                                                  unsigned short* __restrict__ out,
                                                  int Mvalid) {
    int r = blockIdx.x, tid = threadIdx.x;
    unsigned short* y = out + (size_t)r * 768;
    if (r >= Mvalid) { y[tid] = 0; y[tid + 256] = 0; y[tid + 512] = 0; return; }
    const float* x = in + (size_t)r * 768;
    float v0 = x[tid], v1 = x[tid + 256], v2 = x[tid + 512];
    __shared__ float red[4];
    float s = v0 + v1 + v2;
    #pragma unroll
    for (int off = 32; off > 0; off >>= 1) s += __shfl_down(s, off);
    if ((tid & 63) == 0) red[tid >> 6] = s;
    __syncthreads();
    float mean = (red[0] + red[1] + red[2] + red[3]) * (1.0f / 768.0f);
    float d0 = v0 - mean, d1 = v1 - mean, d2 = v2 - mean;
    float q = d0 * d0 + d1 * d1 + d2 * d2;
    __syncthreads();
    #pragma unroll
    for (int off = 32; off > 0; off >>= 1) q += __shfl_down(q, off);
    if ((tid & 63) == 0) red[tid >> 6] = q;
    __syncthreads();
    float var = (red[0] + red[1] + red[2] + red[3]) * (1.0f / 768.0f);
    float rs = rsqrtf(var + 1e-5f);
    y[tid]       = f2bf(d0 * rs * g[tid]       + b[tid]);
    y[tid + 256] = f2bf(d1 * rs * g[tid + 256] + b[tid + 256]);
    y[tid + 512] = f2bf(d2 * rs * g[tid + 512] + b[tid + 512]);
}

// ---------- LayerNorm 768, f32 in -> f32 out (remap for patch rows) ----------
__global__ __launch_bounds__(256) void ln768_k(const float* __restrict__ in,
                                               const float* __restrict__ g,
                                               const float* __restrict__ b,
                                               float* __restrict__ out,
                                               int remap) {
    int r = blockIdx.x, tid = threadIdx.x;
    const float* x = in + (size_t)r * 768;
    float v0 = x[tid], v1 = x[tid + 256], v2 = x[tid + 512];
    __shared__ float red[4];
    float s = v0 + v1 + v2;
    #pragma unroll
    for (int off = 32; off > 0; off >>= 1) s += __shfl_down(s, off);
    if ((tid & 63) == 0) red[tid >> 6] = s;
    __syncthreads();
    float mean = (red[0] + red[1] + red[2] + red[3]) * (1.0f / 768.0f);
    float d0 = v0 - mean, d1 = v1 - mean, d2 = v2 - mean;
    float q = d0 * d0 + d1 * d1 + d2 * d2;
    __syncthreads();
    #pragma unroll
    for (int off = 32; off > 0; off >>= 1) q += __shfl_down(q, off);
    if ((tid & 63) == 0) red[tid >> 6] = q;
    __syncthreads();
    float var = (red[0] + red[1] + red[2] + red[3]) * (1.0f / 768.0f);
    float rs = rsqrtf(var + 1e-5f);
    int orow = remap ? ((r / 1023) * 1024 + 1 + (r % 1023)) : r;
    float* y = out + (size_t)orow * 768;
    y[tid]       = d0 * rs * g[tid]       + b[tid];
    y[tid + 256] = d1 * rs * g[tid + 256] + b[tid + 256];
    y[tid + 512] = d2 * rs * g[tid + 512] + b[tid + 512];
}

// ---------- cls token fill ----------
__global__ void cls_k(const float* __restrict__ cls, float* __restrict__ x) {
    int bi = blockIdx.x, tid = threadIdx.x;
    #pragma unroll
    for (int k = 0; k < 3; ++k)
        x[(size_t)bi * 1024 * 768 + tid + k * 256] = cls[tid + k * 256];
}

// ---------- PEG (depthwise conv + residual + bias) fused with LN -> bf16 ----------
__global__ __launch_bounds__(256) void peg_ln_k(const float* __restrict__ x,
                                                const float* __restrict__ w,
                                                const float* __restrict__ pb,
                                                float* __restrict__ y,
                                                const float* __restrict__ g,
                                                const float* __restrict__ b,
                                                unsigned short* __restrict__ obf) {
    int r = blockIdx.x;
    int i = r & 1023;
    int tid = threadIdx.x;
    const float* xr = x + (size_t)r * 768;
    float* yr = y + (size_t)r * 768;
    float v[3];
    #pragma unroll
    for (int k = 0; k < 3; ++k) {
        int d = tid + k * 256;
        float c  = xr[d];
        float lf = (i > 0)    ? xr[d - 768] : 0.f;
        float rt = (i < 1023) ? xr[d + 768] : 0.f;
        v[k] = c + pb[d] + w[d * 3 + 0] * lf + w[d * 3 + 1] * c + w[d * 3 + 2] * rt;
        yr[d] = v[k];
    }
    __shared__ float red[4];
    float s = v[0] + v[1] + v[2];
    #pragma unroll
    for (int off = 32; off > 0; off >>= 1) s += __shfl_down(s, off);
    if ((tid & 63) == 0) red[tid >> 6] = s;
    __syncthreads();
    float mean = (red[0] + red[1] + red[2] + red[3]) * (1.0f / 768.0f);
    float d0 = v[0] - mean, d1 = v[1] - mean, d2 = v[2] - mean;
    float q = d0 * d0 + d1 * d1 + d2 * d2;
    __syncthreads();
    #pragma unroll
    for (int off = 32; off > 0; off >>= 1) q += __shfl_down(q, off);
    if ((tid & 63) == 0) red[tid >> 6] = q;
    __syncthreads();
    float var = (red[0] + red[1] + red[2] + red[3]) * (1.0f / 768.0f);
    float rs = rsqrtf(var + 1e-5f);
    unsigned short* yb = obf + (size_t)r * 768;
    yb[tid]       = f2bf(d0 * rs * g[tid]       + b[tid]);
    yb[tid + 256] = f2bf(d1 * rs * g[tid + 256] + b[tid + 256]);
    yb[tid + 512] = f2bf(d2 * rs * g[tid + 512] + b[tid + 512]);
}

// ---------- MFMA flash attention, double-buffered K/V LDS (1 barrier/iter) ----------
// Softmax in base-2 domain; XCD-swizzled.
__global__ __launch_bounds__(256) void attn_mfma_k(const unsigned short* __restrict__ qkv,
                                                   const float* __restrict__ mask,
                                                   const unsigned char* __restrict__ flags,
                                                   unsigned short* __restrict__ o) {
    const int bid = blockIdx.x + 16 * blockIdx.y;   // hw dispatch order
    const int t0 = xcd_swz(bid, 384);
    const int qt = t0 & 15, bh = t0 >> 4;
    const int bi = bh / 12, h = bh % 12;
    const int tid = threadIdx.x;
    const int w = tid >> 6, lane = tid & 63;
    const int l16 = lane & 15, lq = lane >> 4;
    const float SC2 = 0.125f * 1.4426950408889634f;   // scale * log2(e)

    __shared__ unsigned short lK[2][64 * 64];
    __shared__ unsigned short lV[2][64 * 64];

    const int q0 = qt * 64;
    const size_t tokbase = (size_t)bi * 1024;
    const int qrow = q0 + w * 16 + l16;

    bf16x8 qb[2];
    {
        const unsigned short* qp = qkv + (tokbase + qrow) * 2304 + h * 64;
        qb[0] = *(const bf16x8*)(qp + lq * 8);
        qb[1] = *(const bf16x8*)(qp + 32 + lq * 8);
    }

    const float* mrow = mask + ((size_t)bh * 1024 + qrow) * 1024;
    const unsigned char* fl = flags + ((size_t)bh * 16 + qt) * 16;

    const int byA = lane * 128 + ((w * 32 +  0) ^ ((lane & 7) << 4));
    const int byB = lane * 128 + ((w * 32 + 16) ^ ((lane & 7) << 4));

    float m_run = -1e30f, l_run = 0.f;     // m_run in base-2 (log2) domain
    f32x4 oacc[4] = {};

    // prologue: stage kt=0 into buffer 0
    {
        const unsigned short* krp = qkv + (tokbase + lane) * 2304 + 768 + h * 64 + w * 16;
        ushort8 kA = *(const ushort8*)krp, kB = *(const ushort8*)(krp + 8);
        ushort8 vA = *(const ushort8*)(krp + 768), vB = *(const ushort8*)(krp + 776);
        *(ushort8*)((char*)&lK[0][0] + byA) = kA;
        *(ushort8*)((char*)&lK[0][0] + byB) = kB;
        #pragma unroll
        for (int j = 0; j < 16; ++j) {
            int row = w * 16 + j;
            int by = row * 128 + ((2 * lane) ^ ((row & 7) << 4));
            *(unsigned short*)((char*)&lV[0][0] + by) = (j < 8) ? (unsigned short)vA[j] : (unsigned short)vB[j - 8];
        }
    }

    for (int kt = 0; kt < 16; ++kt) {
        const int cur = kt & 1;
        const bool triv = fl[kt] != 0;
        __syncthreads();

        ushort8 kA, kB, vA, vB;
        const bool have_next = (kt + 1) < 16;
        if (have_next) {
            const unsigned short* krp = qkv + (tokbase + (kt + 1) * 64 + lane) * 2304 + 768 + h * 64 + w * 16;
            kA = *(const ushort8*)krp;       kB = *(const ushort8*)(krp + 8);
            vA = *(const ushort8*)(krp + 768); vB = *(const ushort8*)(krp + 776);
        }

        // ---- S^T = K @ Q^T ----
        f32x4 sacc[4] = {};
        #pragma unroll
        for (int f = 0; f < 4; ++f) {
            int krow = f * 16 + l16;
            #pragma unroll
            for (int s = 0; s < 2; ++s) {
                int by = krow * 128 + (((s * 64) + lq * 16) ^ ((krow & 7) << 4));
                bf16x8 af = *(const bf16x8*)((const char*)&lK[cur][0] + by);
                sacc[f] = __builtin_amdgcn_mfma_f32_16x16x32_bf16(af, qb[s], sacc[f], 0, 0, 0);
            }
        }

        // ---- mask + scale(log2) + online softmax (lane-local q = l16) ----
        float pv[4][4];
        float smax = -1e30f;
        if (triv) {
            #pragma unroll
            for (int f = 0; f < 4; ++f) {
                pv[f][0] = sacc[f][0] * SC2;
                pv[f][1] = sacc[f][1] * SC2;
                pv[f][2] = sacc[f][2] * SC2;
                pv[f][3] = sacc[f][3] * SC2;
                smax = fmaxf(smax, fmaxf(fmaxf(pv[f][0], pv[f][1]), fmaxf(pv[f][2], pv[f][3])));
            }
        } else {
            #pragma unroll
            for (int f = 0; f < 4; ++f) {
                float4 mk = *(const float4*)(mrow + kt * 64 + f * 16 + lq * 4);
                pv[f][0] = sacc[f][0] * SC2 + (1.f - mk.x) * -1e9f;
                pv[f][1] = sacc[f][1] * SC2 + (1.f - mk.y) * -1e9f;
                pv[f][2] = sacc[f][2] * SC2 + (1.f - mk.z) * -1e9f;
                pv[f][3] = sacc[f][3] * SC2 + (1.f - mk.w) * -1e9f;
                smax = fmaxf(smax, fmaxf(fmaxf(pv[f][0], pv[f][1]), fmaxf(pv[f][2], pv[f][3])));
            }
        }
        smax = fmaxf(smax, __shfl_xor(smax, 16));
        smax = fmaxf(smax, __shfl_xor(smax, 32));
        float m_new = fmaxf(m_run, smax);
        float fac = exp2f(m_run - m_new);
        float lsum = 0.f;
        #pragma unroll
        for (int f = 0; f < 4; ++f) {
            #pragma unroll
            for (int i = 0; i < 4; ++i) {
                pv[f][i] = exp2f(pv[f][i] - m_new);
                lsum += pv[f][i];
            }
        }
        lsum += __shfl_xor(lsum, 16);
        lsum += __shfl_xor(lsum, 32);
        l_run = l_run * fac + lsum;
        m_run = m_new;

        #pragma unroll
        for (int i = 0; i < 4; ++i) {
            float fi = __shfl(fac, 4 * lq + i);
            oacc[0][i] *= fi; oacc[1][i] *= fi; oacc[2][i] *= fi; oacc[3][i] *= fi;
        }

        unsigned wpk[4][2];
        #pragma unroll
        for (int f = 0; f < 4; ++f) {
            wpk[f][0] = (unsigned)f2bf(pv[f][0]) | ((unsigned)f2bf(pv[f][1]) << 16);
            wpk[f][1] = (unsigned)f2bf(pv[f][2]) | ((unsigned)f2bf(pv[f][3]) << 16);
        }

        // ---- O += P @ V ----
        #pragma unroll
        for (int s = 0; s < 2; ++s) {
            unsigned aw[4];
            #pragma unroll
            for (int t = 0; t < 4; ++t) {
                int src = (2 * (lq & 1) + (t >> 1)) * 16 + l16;
                unsigned lo = __shfl(wpk[2 * s][t & 1], src);
                unsigned hi = __shfl(wpk[2 * s + 1][t & 1], src);
                aw[t] = (lq >> 1) ? hi : lo;
            }
            union { unsigned u[4]; bf16x8 v; } pa;
            pa.u[0] = aw[0]; pa.u[1] = aw[1]; pa.u[2] = aw[2]; pa.u[3] = aw[3];
            #pragma unroll
            for (int f = 0; f < 4; ++f) {
                int drow = f * 16 + l16;
                int by = drow * 128 + (((s * 64) + lq * 16) ^ ((drow & 7) << 4));
                bf16x8 vb = *(const bf16x8*)((const char*)&lV[cur][0] + by);
                oacc[f] = __builtin_amdgcn_mfma_f32_16x16x32_bf16(pa.v, vb, oacc[f], 0, 0, 0);
            }
        }

        // ---- write next tile into the inactive buffer ----
        if (have_next) {
            const int nxt = cur ^ 1;
            *(ushort8*)((char*)&lK[nxt][0] + byA) = kA;
            *(ushort8*)((char*)&lK[nxt][0] + byB) = kB;
            #pragma unroll
            for (int j = 0; j < 16; ++j) {
                int row = w * 16 + j;
                int by = row * 128 + ((2 * lane) ^ ((row & 7) << 4));
                *(unsigned short*)((char*)&lV[nxt][0] + by) = (j < 8) ? (unsigned short)vA[j] : (unsigned short)vB[j - 8];
            }
        }
    }

    #pragma unroll
    for (int i = 0; i < 4; ++i) {
        float li = __shfl(l_run, 4 * lq + i);
        float inv = 1.f / li;
        int row = q0 + w * 16 + 4 * lq + i;
        unsigned short* op = o + (tokbase + row) * 768 + h * 64 + l16;
        #pragma unroll
        for (int f = 0; f < 4; ++f)
            op[f * 16] = f2bf(oacc[f][i] * inv);
    }
}

// ---------- GEMM BMx(BN) (full-K, fused epilogue, optional RoPE) ----------
// BM=64, BK=64, 4 waves, gload16 staging (inverse-swizzled source, linear LDS),
// XOR-swizzled ds_read, 2-buffer + __syncthreads, XCD-swizzled blocks.
//   BN=64 : waves 2x2 (FM=2,FN=2), LDS 32KB -> 5 blocks/CU
//   BN=128: waves 1x4 (FM=4,FN=2), LDS 48KB -> 3 blocks/CU, reads/ks 6 for 8 MFMA
template<int BN, bool GELU, bool OBF16, bool ROPE>
__global__ __launch_bounds__(256) void gemm64_k(const unsigned short* __restrict__ A,
                                                const unsigned short* __restrict__ Bt,
                                                const float* __restrict__ bias,
                                                const float* __restrict__ res,
                                                void* __restrict__ Cv,
                                                const float* __restrict__ cosT,
                                                const float* __restrict__ sinT,
                                                int M, int N, int K) {
    constexpr int FM = (BN == 128) ? 4 : 2;
    constexpr int FN = 2;
    __shared__ unsigned short lA[2][64 * 64];
    __shared__ unsigned short lB[2][BN * 64];
    int tid = threadIdx.x;
    int bid = blockIdx.x + gridDim.x * blockIdx.y;
    int t0 = xcd_swz(bid, gridDim.x * gridDim.y);
    int bx = t0 % gridDim.x, by = t0 / gridDim.x;
    int m0 = by * 64, n0 = bx * BN;
    int w = tid >> 6, lane = tid & 63;
    int l16 = lane & 15, lq = lane >> 4;
    int wrow = (BN == 128) ? 0 : (w >> 1) * 32;
    int wcol = (BN == 128) ? (w * 32) : ((w & 1) * 32);

    f32x4 acc[FM][FN] = {};

    auto stage = [&](int buf, int k0) {
        #pragma unroll
        for (int i = 0; i < 2; ++i) {
            int ch = tid + i * 256;
            int r = ch >> 3, c = ch & 7;
            int cs = c ^ (r & 7);
            gload16(A + (size_t)(m0 + r) * K + k0 + cs * 8, &lA[buf][ch * 8]);
        }
        #pragma unroll
        for (int i = 0; i < BN / 32; ++i) {
            int ch = tid + i * 256;
            int r = ch >> 3, c = ch & 7;
            int cs = c ^ (r & 7);
            gload16(Bt + (size_t)(n0 + r) * K + k0 + cs * 8, &lB[buf][ch * 8]);
        }
    };

    const int nk = K >> 6;
    stage(0, 0);
    __syncthreads();
    int cur = 0;
    for (int t = 0; t < nk; ++t) {
        if (t + 1 < nk) stage(cur ^ 1, (t + 1) << 6);
        #pragma unroll
        for (int ks = 0; ks < 2; ++ks) {
            bf16x8 af[FM], bfv[FN];
            #pragma unroll
            for (int fm = 0; fm < FM; ++fm) {
                int row = wrow + fm * 16 + l16;
                int by = row * 128 + ((ks * 64 + lq * 16) ^ ((row & 7) << 4));
                af[fm] = *(const bf16x8*)((const char*)&lA[cur][0] + by);
            }
            #pragma unroll
            for (int fn = 0; fn < FN; ++fn) {
                int row = wcol + fn * 16 + l16;
                int by = row * 128 + ((ks * 64 + lq * 16) ^ ((row & 7) << 4));
                bfv[fn] = *(const bf16x8*)((const char*)&lB[cur][0] + by);
            }
            #pragma unroll
            for (int fm = 0; fm < FM; ++fm)
                #pragma unroll
                for (int fn = 0; fn < FN; ++fn)
                    acc[fm][fn] = __builtin_amdgcn_mfma_f32_16x16x32_bf16(af[fm], bfv[fn], acc[fm][fn], 0, 0, 0);
        }
        __syncthreads();
        cur ^= 1;
    }

    float* Cf = (float*)Cv;
    unsigned short* Cb = (unsigned short*)Cv;
    #pragma unroll
    for (int fm = 0; fm < FM; ++fm)
        #pragma unroll
        for (int fn = 0; fn < FN; ++fn) {
            int col = n0 + wcol + fn * 16 + l16;
            float bv = bias ? bias[col] : 0.f;
            bool rot = ROPE && (col < 1536) && (((wcol + fn * 16) & 63) < 32);  // wave-uniform
            int pidx = ((wcol + fn * 16 + l16) & 63) >> 1;
            #pragma unroll
            for (int i = 0; i < 4; ++i) {
                int row = m0 + wrow + fm * 16 + 4 * lq + i;
                float v = acc[fm][fn][i];
                if (ROPE) {
                    float pr = __shfl_xor(v, 1);
                    if (rot) {
                        int tt = (row & 1023) * 16 + pidx;
                        float c = cosT[tt], s = sinT[tt];
                        v = (l16 & 1) ? (v * c + pr * s) : (v * c - pr * s);
                    }
                }
                if (row < M) {
                    v += bv;
                    if (GELU) v = 0.5f * v * (1.0f + erff(v * 0.70710678118f));
                    if (res)  v += res[(size_t)row * N + col];
                    if (OBF16) Cb[(size_t)row * N + col] = f2bf(v);
                    else       Cf[(size_t)row * N + col] = v;
                }
            }
        }
}

// ---------- GEMM 64x64 split-K (bf16 partials), XCD-swizzled ----------
__global__ __launch_bounds__(256) void gemm64_splitk_k(const unsigned short* __restrict__ A,
                                                       const unsigned short* __restrict__ Bt,
                                                       unsigned short* __restrict__ P,
                                                       int M, int N, int Ktot, int Kc) {
    __shared__ unsigned short lA[2][64 * 64];
    __shared__ unsigned short lB[2][64 * 64];
    int tid = threadIdx.x;
    int bid = blockIdx.x + gridDim.x * (blockIdx.y + gridDim.y * blockIdx.z);
    int t0 = xcd_swz(bid, gridDim.x * gridDim.y * gridDim.z);
    int bx = t0 % gridDim.x;
    int rem = t0 / gridDim.x;
    int by = rem % gridDim.y, bz = rem / gridDim.y;
    int m0 = by * 64, n0 = bx * 64;
    int kb = bz * Kc;
    int w = tid >> 6, lane = tid & 63;
    int l16 = lane & 15, lq = lane >> 4;
    int wrow = (w >> 1) * 32, wcol = (w & 1) * 32;

    f32x4 acc[2][2] = {};

    auto stage = [&](int buf, int k0) {
        #pragma unroll
        for (int i = 0; i < 2; ++i) {
            int ch = tid + i * 256;
            int r = ch >> 3, c = ch & 7;
            int cs = c ^ (r & 7);
            gload16(A + (size_t)(m0 + r) * Ktot + k0 + cs * 8, &lA[buf][ch * 8]);
        }
        #pragma unroll
        for (int i = 0; i < 2; ++i) {
            int ch = tid + i * 256;
            int r = ch >> 3, c = ch & 7;
            int cs = c ^ (r & 7);
            gload16(Bt + (size_t)(n0 + r) * Ktot + k0 + cs * 8, &lB[buf][ch * 8]);
        }
    };

    const int nk = Kc >> 6;
    stage(0, kb);
    __syncthreads();
    int cur = 0;
    for (int t = 0; t < nk; ++t) {
        if (t + 1 < nk) stage(cur ^ 1, kb + ((t + 1) << 6));
        #pragma unroll
        for (int ks = 0; ks < 2; ++ks) {
            bf16x8 af[2], bfv[2];
            #pragma unroll
            for (int fm = 0; fm < 2; ++fm) {
                int row = wrow + fm * 16 + l16;
                int by = row * 128 + ((ks * 64 + lq * 16) ^ ((row & 7) << 4));
                af[fm] = *(const bf16x8*)((const char*)&lA[cur][0] + by);
            }
            #pragma unroll
            for (int fn = 0; fn < 2; ++fn) {
                int row = wcol + fn * 16 + l16;
                int by = row * 128 + ((ks * 64 + lq * 16) ^ ((row & 7) << 4));
                bfv[fn] = *(const bf16x8*)((const char*)&lB[cur][0] + by);
            }
            #pragma unroll
            for (int fm = 0; fm < 2; ++fm)
                #pragma unroll
                for (int fn = 0; fn < 2; ++fn)
                    acc[fm][fn] = __builtin_amdgcn_mfma_f32_16x16x32_bf16(af[fm], bfv[fn], acc[fm][fn], 0, 0, 0);
        }
        __syncthreads();
        cur ^= 1;
    }

    unsigned short* Pz = P + (size_t)bz * M * N;
    #pragma unroll
    for (int fm = 0; fm < 2; ++fm)
        #pragma unroll
        for (int fn = 0; fn < 2; ++fn) {
            int col = n0 + wcol + fn * 16 + l16;
            #pragma unroll
            for (int i = 0; i < 4; ++i) {
                int row = m0 + wrow + fm * 16 + 4 * lq + i;
                Pz[(size_t)row * N + col] = f2bf(acc[fm][fn][i]);
            }
        }
}

// ---------- split-K reduce (bf16 partials, vectorized) + bias + residual + LN ----------
template<int NP>
__global__ __launch_bounds__(256) void redsum_ln_k(const unsigned short* __restrict__ P,
                                                   const float* __restrict__ bias,
                                                   const float* __restrict__ res,
                                                   float* __restrict__ outf,
                                                   const float* __restrict__ g,
                                                   const float* __restrict__ b,
                                                   unsigned short* __restrict__ obf) {
    const size_t MN = (size_t)2048 * 768;
    int r = blockIdx.x, tid = threadIdx.x;
    int col = tid * 4;
    size_t idx = (size_t)r * 768 + col;
    float v0 = 0.f, v1 = 0.f, v2 = 0.f, v3 = 0.f;
    if (tid < 192) {
        float4 a4 = *(const float4*)(res + idx);
        float4 b4 = *(const float4*)(bias + col);
        v0 = a4.x + b4.x; v1 = a4.y + b4.y; v2 = a4.z + b4.z; v3 = a4.w + b4.w;
        #pragma unroll
        for (int pz = 0; pz < NP; ++pz) {
            ushort4 p4 = *(const ushort4*)(P + (size_t)pz * MN + idx);
            v0 += bf2f(p4.x); v1 += bf2f(p4.y); v2 += bf2f(p4.z); v3 += bf2f(p4.w);
        }
        float4 o4; o4.x = v0; o4.y = v1; o4.z = v2; o4.w = v3;
        *(float4*)(outf + idx) = o4;
    }
    if (!g) return;                      // block-uniform
    __shared__ float red[4];
    float s = v0 + v1 + v2 + v3;
    #pragma unroll
    for (int off = 32; off > 0; off >>= 1) s += __shfl_down(s, off);
    if ((tid & 63) == 0) red[tid >> 6] = s;
    __syncthreads();
    float mean = (red[0] + red[1] + red[2] + red[3]) * (1.0f / 768.0f);
    float d0 = v0 - mean, d1 = v1 - mean, d2 = v2 - mean, d3 = v3 - mean;
    float q = (tid < 192) ? (d0 * d0 + d1 * d1 + d2 * d2 + d3 * d3) : 0.f;
    __syncthreads();
    #pragma unroll
    for (int off = 32; off > 0; off >>= 1) q += __shfl_down(q, off);
    if ((tid & 63) == 0) red[tid >> 6] = q;
    __syncthreads();
    float var = (red[0] + red[1] + red[2] + red[3]) * (1.0f / 768.0f);
    float rs = rsqrtf(var + 1e-5f);
    if (tid < 192) {
        float4 g4 = *(const float4*)(g + col);
        float4 bb4 = *(const float4*)(b + col);
        ushort4 y4;
        y4.x = f2bf(d0 * rs * g4.x + bb4.x);
        y4.y = f2bf(d1 * rs * g4.y + bb4.y);
        y4.z = f2bf(d2 * rs * g4.z + bb4.z);
        y4.w = f2bf(d3 * rs * g4.w + bb4.w);
        *(ushort4*)(obf + idx) = y4;
    }
}

// ---------- launch ----------
extern "C" void kernel_launch(void* const* d_in, const int* in_sizes, int n_in,
                              void* d_out, int out_size, void* d_ws, size_t ws_size,
                              hipStream_t stream) {
    const float* filaments = (const float*)d_in[0];
    const float* mask      = (const float*)d_in[1];
    const float* ln_p1_g   = (const float*)d_in[2];
    const float* ln_p1_b   = (const float*)d_in[3];
    const float* W_patch   = (const float*)d_in[4];
    const float* b_patch   = (const float*)d_in[5];
    const float* ln_p2_g   = (const float*)d_in[6];
    const float* ln_p2_b   = (const float*)d_in[7];
    const float* peg_w     = (const float*)d_in[8];
    const float* peg_b     = (const float*)d_in[9];
    const float* cls_token = (const float*)d_in[10];
    const float* ln_a_g    = (const float*)d_in[11];
    const float* ln_a_b    = (const float*)d_in[12];
    const float* W_qkv     = (const float*)d_in[13];
    const float* W_o       = (const float*)d_in[14];
    const float* b_o       = (const float*)d_in[15];
    const float* inv_freq  = (const float*)d_in[16];
    const float* ln_f_g    = (const float*)d_in[17];
    const float* ln_f_b    = (const float*)d_in[18];
    const float* W1        = (const float*)d_in[19];
    const float* b1        = (const float*)d_in[20];
    const float* W2        = (const float*)d_in[21];
    const float* b2        = (const float*)d_in[22];

    // ---- workspace layout (~104 MB of ~400 MB) ----
    char* p = (char*)d_ws;
    float* xa            = (float*)p;          p += 2048 * 768 * 4;
    float* xb            = (float*)p;          p += 2048 * 768 * 4;
    unsigned short* h_bf = (unsigned short*)p; p += 2048 * 768 * 2;
    unsigned short* qkv  = (unsigned short*)p; p += 2048 * 3072 * 2;   // qkv / m_bf / patch-tmp overlay
    unsigned short* Pbuf = (unsigned short*)p; p += (size_t)4 * 2048 * 768 * 2;
    unsigned short* w1t  = (unsigned short*)p; p += (size_t)6 * 3072 * 768 * 2;
    unsigned short* w2t  = (unsigned short*)p; p += (size_t)6 * 3072 * 768 * 2;
    unsigned short* wqt  = (unsigned short*)p; p += 2304 * 768 * 2;
    unsigned short* wot  = (unsigned short*)p; p += 768 * 768 * 2;
    unsigned short* wpt  = (unsigned short*)p; p += 768 * 768 * 2;
    float* cosT          = (float*)p;          p += 16384 * 4;
    float* sinT          = (float*)p;          p += 16384 * 4;
    unsigned char* flags = (unsigned char*)p;  p += 8192;
    unsigned short* m_bf = qkv;
    float* tmp = (float*)qkv;                  // patch GEMM f32 out
    float* out = (float*)d_out;

    // ---- one-time precomputes ----
    mask_flags_k<<<6144, 256, 0, stream>>>(mask, flags);
    cossin_k<<<64, 256, 0, stream>>>(inv_freq, cosT, sinT);
    wt_cast_k<<<dim3(12, 12), 256, 0, stream>>>(W_patch, wpt, 768, 768);
    wt_cast_k<<<dim3(36, 12), 256, 0, stream>>>(W_qkv,  wqt, 768, 2304);
    wt_cast_k<<<dim3(12, 12), 256, 0, stream>>>(W_o,    wot, 768, 768);
    wt_cast_k<<<dim3(48, 12, 6), 256, 0, stream>>>(W1, w1t, 768, 3072);
    wt_cast_k<<<dim3(12, 48, 6), 256, 0, stream>>>(W2, w2t, 3072, 768);

    // ---- patch embed ----
    ln768_bf_k<<<2048, 256, 0, stream>>>(filaments, ln_p1_g, ln_p1_b, h_bf, 2046);
    gemm64_k<64, false, false, false><<<dim3(12, 32), 256, 0, stream>>>(h_bf, wpt, b_patch, nullptr, tmp,
                                                                        nullptr, nullptr, 2046, 768, 768);
    ln768_k<<<2046, 256, 0, stream>>>(tmp, ln_p2_g, ln_p2_b, xa, 1);
    cls_k<<<2, 256, 0, stream>>>(cls_token, xa);
    peg_ln_k<<<2048, 256, 0, stream>>>(xa, peg_w, peg_b, xb, ln_a_g, ln_a_b, h_bf);

    float* cur = xb;
    float* nxt = xa;
    for (int i = 0; i < 6; ++i) {
        // qkv projection with fused RoPE (h_bf holds ln_a(x)); 64x128 tile
        gemm64_k<128, false, true, true><<<dim3(18, 32), 256, 0, stream>>>(h_bf, wqt, nullptr, nullptr, qkv,
                                                                           cosT, sinT, 2048, 2304, 768);
        attn_mfma_k<<<dim3(16, 24), 256, 0, stream>>>(qkv, mask, flags, h_bf);
        // o-proj: split-K x2 + fused reduce (bias + residual) + ln_f -> h_bf
        gemm64_splitk_k<<<dim3(12, 32, 2), 256, 0, stream>>>(h_bf, wot, Pbuf, 2048, 768, 768, 384);
        redsum_ln_k<2><<<2048, 256, 0, stream>>>(Pbuf, b_o, cur, nxt,
                                                 ln_f_g + i * 768, ln_f_b + i * 768, h_bf);
        // MLP; mlp1 at 64x128 tile
        gemm64_k<128, true, true, false><<<dim3(24, 32), 256, 0, stream>>>(h_bf, w1t + (size_t)i * 3072 * 768, b1 + i * 3072,
                                                                           nullptr, m_bf, nullptr, nullptr, 2048, 3072, 768);
        gemm64_splitk_k<<<dim3(12, 32, 4), 256, 0, stream>>>(m_bf, w2t + (size_t)i * 768 * 3072, Pbuf, 2048, 768, 3072, 768);
        redsum_ln_k<4><<<2048, 256, 0, stream>>>(Pbuf, b2 + i * 768, nxt, (i == 5) ? out : cur,
                                                 (i < 5) ? (ln_a_g + (i + 1) * 768) : nullptr,
                                                 (i < 5) ? (ln_a_b + (i + 1) * 768) : nullptr, h_bf);
    }
}

// Round 19
// 769.833 us; speedup vs baseline: 1.0175x; 1.0175x over previous
//
#include <hip/hip_runtime.h>
#include <hip/hip_bf16.h>
#include <math.h>

// ---------- types ----------
typedef __attribute__((ext_vector_type(8))) short          bf16x8;
typedef __attribute__((ext_vector_type(8))) unsigned short ushort8;
typedef __attribute__((ext_vector_type(4))) float          f32x4;

__device__ __forceinline__ unsigned short f2bf(float f) {
    union { float f; unsigned u; } v; v.f = f;
    unsigned u = v.u;
    unsigned r = (u + 0x7FFFu + ((u >> 16) & 1u)) >> 16;   // RNE
    return (unsigned short)r;
}
__device__ __forceinline__ float bf2f(unsigned short h) {
    union { unsigned u; float f; } v; v.u = ((unsigned)h) << 16;
    return v.f;
}

// async global->LDS, 16B per lane (m97 pattern)
__device__ __forceinline__ void gload16(const void* g, void* l) {
    __builtin_amdgcn_global_load_lds(
        (const __attribute__((address_space(1))) void*)g,
        (__attribute__((address_space(3))) void*)l, 16, 0, 0);
}

// XCD-aware bijective block remap (requires nwg % 8 == 0)
__device__ __forceinline__ int xcd_swz(int bid, int nwg) {
    return (bid & 7) * (nwg >> 3) + (bid >> 3);
}

// ---------- weight transpose-cast: in[K][N] f32 -> out[N][K] bf16 ----------
__global__ __launch_bounds__(256) void wt_cast_k(const float* __restrict__ in,
                                                 unsigned short* __restrict__ out,
                                                 int K, int N) {
    __shared__ float t[64][65];
    in  += (size_t)blockIdx.z * K * N;
    out += (size_t)blockIdx.z * K * N;
    int n0 = blockIdx.x * 64, k0 = blockIdx.y * 64;
    int tx = threadIdx.x & 63, ty = threadIdx.x >> 6;
    #pragma unroll
    for (int p = 0; p < 16; ++p) {
        int k = ty + p * 4;
        t[k][tx] = in[(size_t)(k0 + k) * N + n0 + tx];
    }
    __syncthreads();
    #pragma unroll
    for (int p = 0; p < 16; ++p) {
        int n = ty + p * 4;
        out[(size_t)(n0 + n) * K + k0 + tx] = f2bf(t[tx][n]);
    }
}

// ---------- cos/sin table for RoPE: [1024][16] ----------
__global__ __launch_bounds__(256) void cossin_k(const float* __restrict__ inv_freq,
                                                float* __restrict__ cosT,
                                                float* __restrict__ sinT) {
    int idx = blockIdx.x * 256 + threadIdx.x;     // 16384
    int t = idx >> 4, p = idx & 15;
    float fr = (float)t * inv_freq[p];
    cosT[idx] = cosf(fr);
    sinT[idx] = sinf(fr);
}

// ---------- mask triviality flags ----------
__global__ __launch_bounds__(256) void mask_flags_k(const float* __restrict__ mask,
                                                    unsigned char* __restrict__ flags) {
    int idx = blockIdx.x;                    // (bh*16 + qt)*16 + kt
    int tid = threadIdx.x;
    int kt = idx & 15, qt = (idx >> 4) & 15, bh = idx >> 8;
    int r = tid >> 2, cc = (tid & 3) * 16;
    const float* prow = mask + ((size_t)bh * 1024 + (size_t)qt * 64 + r) * 1024 + kt * 64 + cc;
    int bad = 0;
    #pragma unroll
    for (int j = 0; j < 4; ++j) {
        float4 v = *(const float4*)(prow + j * 4);
        bad |= (v.x != 1.f) || (v.y != 1.f) || (v.z != 1.f) || (v.w != 1.f);
    }
    __shared__ int sb[4];
    unsigned long long anyb = __ballot(bad != 0);
    if ((tid & 63) == 0) sb[tid >> 6] = (anyb != 0ull) ? 1 : 0;
    __syncthreads();
    if (tid == 0) flags[idx] = (unsigned char)(!(sb[0] | sb[1] | sb[2] | sb[3]));
}

// ---------- LayerNorm 768, f32 in -> bf16 out ----------
__global__ __launch_bounds__(256) void ln768_bf_k(const float* __restrict__ in,
                                                  const float* __restrict__ g,
                                                  const float* __restrict__ b,
                                                  unsigned short* __restrict__ out,
                                                  int Mvalid) {
    int r = blockIdx.x, tid = threadIdx.x;
    unsigned short* y = out + (size_t)r * 768;
    if (r >= Mvalid) { y[tid] = 0; y[tid + 256] = 0; y[tid + 512] = 0; return; }
    const float* x = in + (size_t)r * 768;
    float v0 = x[tid], v1 = x[tid + 256], v2 = x[tid + 512];
    __shared__ float red[4];
    float s = v0 + v1 + v2;
    #pragma unroll
    for (int off = 32; off > 0; off >>= 1) s += __shfl_down(s, off);
    if ((tid & 63) == 0) red[tid >> 6] = s;
    __syncthreads();
    float mean = (red[0] + red[1] + red[2] + red[3]) * (1.0f / 768.0f);
    float d0 = v0 - mean, d1 = v1 - mean, d2 = v2 - mean;
    float q = d0 * d0 + d1 * d1 + d2 * d2;
    __syncthreads();
    #pragma unroll
    for (int off = 32; off > 0; off >>= 1) q += __shfl_down(q, off);
    if ((tid & 63) == 0) red[tid >> 6] = q;
    __syncthreads();
    float var = (red[0] + red[1] + red[2] + red[3]) * (1.0f / 768.0f);
    float rs = rsqrtf(var + 1e-5f);
    y[tid]       = f2bf(d0 * rs * g[tid]       + b[tid]);
    y[tid + 256] = f2bf(d1 * rs * g[tid + 256] + b[tid + 256]);
    y[tid + 512] = f2bf(d2 * rs * g[tid + 512] + b[tid + 512]);
}

// ---------- LayerNorm 768, f32 in -> f32 out (remap for patch rows) ----------
__global__ __launch_bounds__(256) void ln768_k(const float* __restrict__ in,
                                               const float* __restrict__ g,
                                               const float* __restrict__ b,
                                               float* __restrict__ out,
                                               int remap) {
    int r = blockIdx.x, tid = threadIdx.x;
    const float* x = in + (size_t)r * 768;
    float v0 = x[tid], v1 = x[tid + 256], v2 = x[tid + 512];
    __shared__ float red[4];
    float s = v0 + v1 + v2;
    #pragma unroll
    for (int off = 32; off > 0; off >>= 1) s += __shfl_down(s, off);
    if ((tid & 63) == 0) red[tid >> 6] = s;
    __syncthreads();
    float mean = (red[0] + red[1] + red[2] + red[3]) * (1.0f / 768.0f);
    float d0 = v0 - mean, d1 = v1 - mean, d2 = v2 - mean;
    float q = d0 * d0 + d1 * d1 + d2 * d2;
    __syncthreads();
    #pragma unroll
    for (int off = 32; off > 0; off >>= 1) q += __shfl_down(q, off);
    if ((tid & 63) == 0) red[tid >> 6] = q;
    __syncthreads();
    float var = (red[0] + red[1] + red[2] + red[3]) * (1.0f / 768.0f);
    float rs = rsqrtf(var + 1e-5f);
    int orow = remap ? ((r / 1023) * 1024 + 1 + (r % 1023)) : r;
    float* y = out + (size_t)orow * 768;
    y[tid]       = d0 * rs * g[tid]       + b[tid];
    y[tid + 256] = d1 * rs * g[tid + 256] + b[tid + 256];
    y[tid + 512] = d2 * rs * g[tid + 512] + b[tid + 512];
}

// ---------- cls token fill ----------
__global__ void cls_k(const float* __restrict__ cls, float* __restrict__ x) {
    int bi = blockIdx.x, tid = threadIdx.x;
    #pragma unroll
    for (int k = 0; k < 3; ++k)
        x[(size_t)bi * 1024 * 768 + tid + k * 256] = cls[tid + k * 256];
}

// ---------- PEG (depthwise conv + residual + bias) fused with LN -> bf16 ----------
__global__ __launch_bounds__(256) void peg_ln_k(const float* __restrict__ x,
                                                const float* __restrict__ w,
                                                const float* __restrict__ pb,
                                                float* __restrict__ y,
                                                const float* __restrict__ g,
                                                const float* __restrict__ b,
                                                unsigned short* __restrict__ obf) {
    int r = blockIdx.x;
    int i = r & 1023;
    int tid = threadIdx.x;
    const float* xr = x + (size_t)r * 768;
    float* yr = y + (size_t)r * 768;
    float v[3];
    #pragma unroll
    for (int k = 0; k < 3; ++k) {
        int d = tid + k * 256;
        float c  = xr[d];
        float lf = (i > 0)    ? xr[d - 768] : 0.f;
        float rt = (i < 1023) ? xr[d + 768] : 0.f;
        v[k] = c + pb[d] + w[d * 3 + 0] * lf + w[d * 3 + 1] * c + w[d * 3 + 2] * rt;
        yr[d] = v[k];
    }
    __shared__ float red[4];
    float s = v[0] + v[1] + v[2];
    #pragma unroll
    for (int off = 32; off > 0; off >>= 1) s += __shfl_down(s, off);
    if ((tid & 63) == 0) red[tid >> 6] = s;
    __syncthreads();
    float mean = (red[0] + red[1] + red[2] + red[3]) * (1.0f / 768.0f);
    float d0 = v[0] - mean, d1 = v[1] - mean, d2 = v[2] - mean;
    float q = d0 * d0 + d1 * d1 + d2 * d2;
    __syncthreads();
    #pragma unroll
    for (int off = 32; off > 0; off >>= 1) q += __shfl_down(q, off);
    if ((tid & 63) == 0) red[tid >> 6] = q;
    __syncthreads();
    float var = (red[0] + red[1] + red[2] + red[3]) * (1.0f / 768.0f);
    float rs = rsqrtf(var + 1e-5f);
    unsigned short* yb = obf + (size_t)r * 768;
    yb[tid]       = f2bf(d0 * rs * g[tid]       + b[tid]);
    yb[tid + 256] = f2bf(d1 * rs * g[tid + 256] + b[tid + 256]);
    yb[tid + 512] = f2bf(d2 * rs * g[tid + 512] + b[tid + 512]);
}

// ---------- MFMA flash attention, double-buffered K/V LDS (1 barrier/iter) ----------
// Softmax in base-2 domain; XCD-swizzled.
__global__ __launch_bounds__(256) void attn_mfma_k(const unsigned short* __restrict__ qkv,
                                                   const float* __restrict__ mask,
                                                   const unsigned char* __restrict__ flags,
                                                   unsigned short* __restrict__ o) {
    const int bid = blockIdx.x + 16 * blockIdx.y;   // hw dispatch order
    const int t0 = xcd_swz(bid, 384);
    const int qt = t0 & 15, bh = t0 >> 4;
    const int bi = bh / 12, h = bh % 12;
    const int tid = threadIdx.x;
    const int w = tid >> 6, lane = tid & 63;
    const int l16 = lane & 15, lq = lane >> 4;
    const float SC2 = 0.125f * 1.4426950408889634f;   // scale * log2(e)

    __shared__ unsigned short lK[2][64 * 64];
    __shared__ unsigned short lV[2][64 * 64];

    const int q0 = qt * 64;
    const size_t tokbase = (size_t)bi * 1024;
    const int qrow = q0 + w * 16 + l16;

    bf16x8 qb[2];
    {
        const unsigned short* qp = qkv + (tokbase + qrow) * 2304 + h * 64;
        qb[0] = *(const bf16x8*)(qp + lq * 8);
        qb[1] = *(const bf16x8*)(qp + 32 + lq * 8);
    }

    const float* mrow = mask + ((size_t)bh * 1024 + qrow) * 1024;
    const unsigned char* fl = flags + ((size_t)bh * 16 + qt) * 16;

    const int byA = lane * 128 + ((w * 32 +  0) ^ ((lane & 7) << 4));
    const int byB = lane * 128 + ((w * 32 + 16) ^ ((lane & 7) << 4));

    float m_run = -1e30f, l_run = 0.f;     // m_run in base-2 (log2) domain
    f32x4 oacc[4] = {};

    // prologue: stage kt=0 into buffer 0
    {
        const unsigned short* krp = qkv + (tokbase + lane) * 2304 + 768 + h * 64 + w * 16;
        ushort8 kA = *(const ushort8*)krp, kB = *(const ushort8*)(krp + 8);
        ushort8 vA = *(const ushort8*)(krp + 768), vB = *(const ushort8*)(krp + 776);
        *(ushort8*)((char*)&lK[0][0] + byA) = kA;
        *(ushort8*)((char*)&lK[0][0] + byB) = kB;
        #pragma unroll
        for (int j = 0; j < 16; ++j) {
            int row = w * 16 + j;
            int by = row * 128 + ((2 * lane) ^ ((row & 7) << 4));
            *(unsigned short*)((char*)&lV[0][0] + by) = (j < 8) ? (unsigned short)vA[j] : (unsigned short)vB[j - 8];
        }
    }

    for (int kt = 0; kt < 16; ++kt) {
        const int cur = kt & 1;
        const bool triv = fl[kt] != 0;
        __syncthreads();

        ushort8 kA, kB, vA, vB;
        const bool have_next = (kt + 1) < 16;
        if (have_next) {
            const unsigned short* krp = qkv + (tokbase + (kt + 1) * 64 + lane) * 2304 + 768 + h * 64 + w * 16;
            kA = *(const ushort8*)krp;       kB = *(const ushort8*)(krp + 8);
            vA = *(const ushort8*)(krp + 768); vB = *(const ushort8*)(krp + 776);
        }

        // ---- S^T = K @ Q^T ----
        f32x4 sacc[4] = {};
        #pragma unroll
        for (int f = 0; f < 4; ++f) {
            int krow = f * 16 + l16;
            #pragma unroll
            for (int s = 0; s < 2; ++s) {
                int by = krow * 128 + (((s * 64) + lq * 16) ^ ((krow & 7) << 4));
                bf16x8 af = *(const bf16x8*)((const char*)&lK[cur][0] + by);
                sacc[f] = __builtin_amdgcn_mfma_f32_16x16x32_bf16(af, qb[s], sacc[f], 0, 0, 0);
            }
        }

        // ---- mask + scale(log2) + online softmax (lane-local q = l16) ----
        float pv[4][4];
        float smax = -1e30f;
        if (triv) {
            #pragma unroll
            for (int f = 0; f < 4; ++f) {
                pv[f][0] = sacc[f][0] * SC2;
                pv[f][1] = sacc[f][1] * SC2;
                pv[f][2] = sacc[f][2] * SC2;
                pv[f][3] = sacc[f][3] * SC2;
                smax = fmaxf(smax, fmaxf(fmaxf(pv[f][0], pv[f][1]), fmaxf(pv[f][2], pv[f][3])));
            }
        } else {
            #pragma unroll
            for (int f = 0; f < 4; ++f) {
                float4 mk = *(const float4*)(mrow + kt * 64 + f * 16 + lq * 4);
                pv[f][0] = sacc[f][0] * SC2 + (1.f - mk.x) * -1e9f;
                pv[f][1] = sacc[f][1] * SC2 + (1.f - mk.y) * -1e9f;
                pv[f][2] = sacc[f][2] * SC2 + (1.f - mk.z) * -1e9f;
                pv[f][3] = sacc[f][3] * SC2 + (1.f - mk.w) * -1e9f;
                smax = fmaxf(smax, fmaxf(fmaxf(pv[f][0], pv[f][1]), fmaxf(pv[f][2], pv[f][3])));
            }
        }
        smax = fmaxf(smax, __shfl_xor(smax, 16));
        smax = fmaxf(smax, __shfl_xor(smax, 32));
        float m_new = fmaxf(m_run, smax);
        float fac = exp2f(m_run - m_new);
        float lsum = 0.f;
        #pragma unroll
        for (int f = 0; f < 4; ++f) {
            #pragma unroll
            for (int i = 0; i < 4; ++i) {
                pv[f][i] = exp2f(pv[f][i] - m_new);
                lsum += pv[f][i];
            }
        }
        lsum += __shfl_xor(lsum, 16);
        lsum += __shfl_xor(lsum, 32);
        l_run = l_run * fac + lsum;
        m_run = m_new;

        #pragma unroll
        for (int i = 0; i < 4; ++i) {
            float fi = __shfl(fac, 4 * lq + i);
            oacc[0][i] *= fi; oacc[1][i] *= fi; oacc[2][i] *= fi; oacc[3][i] *= fi;
        }

        unsigned wpk[4][2];
        #pragma unroll
        for (int f = 0; f < 4; ++f) {
            wpk[f][0] = (unsigned)f2bf(pv[f][0]) | ((unsigned)f2bf(pv[f][1]) << 16);
            wpk[f][1] = (unsigned)f2bf(pv[f][2]) | ((unsigned)f2bf(pv[f][3]) << 16);
        }

        // ---- O += P @ V ----
        #pragma unroll
        for (int s = 0; s < 2; ++s) {
            unsigned aw[4];
            #pragma unroll
            for (int t = 0; t < 4; ++t) {
                int src = (2 * (lq & 1) + (t >> 1)) * 16 + l16;
                unsigned lo = __shfl(wpk[2 * s][t & 1], src);
                unsigned hi = __shfl(wpk[2 * s + 1][t & 1], src);
                aw[t] = (lq >> 1) ? hi : lo;
            }
            union { unsigned u[4]; bf16x8 v; } pa;
            pa.u[0] = aw[0]; pa.u[1] = aw[1]; pa.u[2] = aw[2]; pa.u[3] = aw[3];
            #pragma unroll
            for (int f = 0; f < 4; ++f) {
                int drow = f * 16 + l16;
                int by = drow * 128 + (((s * 64) + lq * 16) ^ ((drow & 7) << 4));
                bf16x8 vb = *(const bf16x8*)((const char*)&lV[cur][0] + by);
                oacc[f] = __builtin_amdgcn_mfma_f32_16x16x32_bf16(pa.v, vb, oacc[f], 0, 0, 0);
            }
        }

        // ---- write next tile into the inactive buffer ----
        if (have_next) {
            const int nxt = cur ^ 1;
            *(ushort8*)((char*)&lK[nxt][0] + byA) = kA;
            *(ushort8*)((char*)&lK[nxt][0] + byB) = kB;
            #pragma unroll
            for (int j = 0; j < 16; ++j) {
                int row = w * 16 + j;
                int by = row * 128 + ((2 * lane) ^ ((row & 7) << 4));
                *(unsigned short*)((char*)&lV[nxt][0] + by) = (j < 8) ? (unsigned short)vA[j] : (unsigned short)vB[j - 8];
            }
        }
    }

    #pragma unroll
    for (int i = 0; i < 4; ++i) {
        float li = __shfl(l_run, 4 * lq + i);
        float inv = 1.f / li;
        int row = q0 + w * 16 + 4 * lq + i;
        unsigned short* op = o + (tokbase + row) * 768 + h * 64 + l16;
        #pragma unroll
        for (int f = 0; f < 4; ++f)
            op[f * 16] = f2bf(oacc[f][i] * inv);
    }
}

// ---------- GEMM BMx(BN) (full-K, fused epilogue, optional RoPE) ----------
//   BN=64 : waves 2x2 (FM=2,FN=2), LDS 32KB -> 5 blocks/CU
//   BN=128: waves 1x4 (FM=4,FN=2), LDS 48KB -> 3 blocks/CU, reads/ks 6 for 8 MFMA
template<int BN, bool GELU, bool OBF16, bool ROPE>
__global__ __launch_bounds__(256) void gemm64_k(const unsigned short* __restrict__ A,
                                                const unsigned short* __restrict__ Bt,
                                                const float* __restrict__ bias,
                                                const float* __restrict__ res,
                                                void* __restrict__ Cv,
                                                const float* __restrict__ cosT,
                                                const float* __restrict__ sinT,
                                                int M, int N, int K) {
    constexpr int FM = (BN == 128) ? 4 : 2;
    constexpr int FN = 2;
    __shared__ unsigned short lA[2][64 * 64];
    __shared__ unsigned short lB[2][BN * 64];
    int tid = threadIdx.x;
    int bid = blockIdx.x + gridDim.x * blockIdx.y;
    int t0 = xcd_swz(bid, gridDim.x * gridDim.y);
    int bx = t0 % gridDim.x, by = t0 / gridDim.x;
    int m0 = by * 64, n0 = bx * BN;
    int w = tid >> 6, lane = tid & 63;
    int l16 = lane & 15, lq = lane >> 4;
    int wrow = (BN == 128) ? 0 : (w >> 1) * 32;
    int wcol = (BN == 128) ? (w * 32) : ((w & 1) * 32);

    f32x4 acc[FM][FN] = {};

    auto stage = [&](int buf, int k0) {
        #pragma unroll
        for (int i = 0; i < 2; ++i) {
            int ch = tid + i * 256;
            int r = ch >> 3, c = ch & 7;
            int cs = c ^ (r & 7);
            gload16(A + (size_t)(m0 + r) * K + k0 + cs * 8, &lA[buf][ch * 8]);
        }
        #pragma unroll
        for (int i = 0; i < BN / 32; ++i) {
            int ch = tid + i * 256;
            int r = ch >> 3, c = ch & 7;
            int cs = c ^ (r & 7);
            gload16(Bt + (size_t)(n0 + r) * K + k0 + cs * 8, &lB[buf][ch * 8]);
        }
    };

    const int nk = K >> 6;
    stage(0, 0);
    __syncthreads();
    int cur = 0;
    for (int t = 0; t < nk; ++t) {
        if (t + 1 < nk) stage(cur ^ 1, (t + 1) << 6);
        #pragma unroll
        for (int ks = 0; ks < 2; ++ks) {
            bf16x8 af[FM], bfv[FN];
            #pragma unroll
            for (int fm = 0; fm < FM; ++fm) {
                int row = wrow + fm * 16 + l16;
                int by = row * 128 + ((ks * 64 + lq * 16) ^ ((row & 7) << 4));
                af[fm] = *(const bf16x8*)((const char*)&lA[cur][0] + by);
            }
            #pragma unroll
            for (int fn = 0; fn < FN; ++fn) {
                int row = wcol + fn * 16 + l16;
                int by = row * 128 + ((ks * 64 + lq * 16) ^ ((row & 7) << 4));
                bfv[fn] = *(const bf16x8*)((const char*)&lB[cur][0] + by);
            }
            #pragma unroll
            for (int fm = 0; fm < FM; ++fm)
                #pragma unroll
                for (int fn = 0; fn < FN; ++fn)
                    acc[fm][fn] = __builtin_amdgcn_mfma_f32_16x16x32_bf16(af[fm], bfv[fn], acc[fm][fn], 0, 0, 0);
        }
        __syncthreads();
        cur ^= 1;
    }

    float* Cf = (float*)Cv;
    unsigned short* Cb = (unsigned short*)Cv;
    #pragma unroll
    for (int fm = 0; fm < FM; ++fm)
        #pragma unroll
        for (int fn = 0; fn < FN; ++fn) {
            int col = n0 + wcol + fn * 16 + l16;
            float bv = bias ? bias[col] : 0.f;
            bool rot = ROPE && (col < 1536) && (((wcol + fn * 16) & 63) < 32);  // wave-uniform
            int pidx = ((wcol + fn * 16 + l16) & 63) >> 1;
            #pragma unroll
            for (int i = 0; i < 4; ++i) {
                int row = m0 + wrow + fm * 16 + 4 * lq + i;
                float v = acc[fm][fn][i];
                if (ROPE) {
                    float pr = __shfl_xor(v, 1);
                    if (rot) {
                        int tt = (row & 1023) * 16 + pidx;
                        float c = cosT[tt], s = sinT[tt];
                        v = (l16 & 1) ? (v * c + pr * s) : (v * c - pr * s);
                    }
                }
                if (row < M) {
                    v += bv;
                    if (GELU) v = 0.5f * v * (1.0f + erff(v * 0.70710678118f));
                    if (res)  v += res[(size_t)row * N + col];
                    if (OBF16) Cb[(size_t)row * N + col] = f2bf(v);
                    else       Cf[(size_t)row * N + col] = v;
                }
            }
        }
}

// ---------- GEMM BMx(BN) split-K (bf16 partials), XCD-swizzled ----------
template<int BN>
__global__ __launch_bounds__(256) void gemm64_splitk_k(const unsigned short* __restrict__ A,
                                                       const unsigned short* __restrict__ Bt,
                                                       unsigned short* __restrict__ P,
                                                       int M, int N, int Ktot, int Kc) {
    constexpr int FM = (BN == 128) ? 4 : 2;
    constexpr int FN = 2;
    __shared__ unsigned short lA[2][64 * 64];
    __shared__ unsigned short lB[2][BN * 64];
    int tid = threadIdx.x;
    int bid = blockIdx.x + gridDim.x * (blockIdx.y + gridDim.y * blockIdx.z);
    int t0 = xcd_swz(bid, gridDim.x * gridDim.y * gridDim.z);
    int bx = t0 % gridDim.x;
    int rem = t0 / gridDim.x;
    int by = rem % gridDim.y, bz = rem / gridDim.y;
    int m0 = by * 64, n0 = bx * BN;
    int kb = bz * Kc;
    int w = tid >> 6, lane = tid & 63;
    int l16 = lane & 15, lq = lane >> 4;
    int wrow = (BN == 128) ? 0 : (w >> 1) * 32;
    int wcol = (BN == 128) ? (w * 32) : ((w & 1) * 32);

    f32x4 acc[FM][FN] = {};

    auto stage = [&](int buf, int k0) {
        #pragma unroll
        for (int i = 0; i < 2; ++i) {
            int ch = tid + i * 256;
            int r = ch >> 3, c = ch & 7;
            int cs = c ^ (r & 7);
            gload16(A + (size_t)(m0 + r) * Ktot + k0 + cs * 8, &lA[buf][ch * 8]);
        }
        #pragma unroll
        for (int i = 0; i < BN / 32; ++i) {
            int ch = tid + i * 256;
            int r = ch >> 3, c = ch & 7;
            int cs = c ^ (r & 7);
            gload16(Bt + (size_t)(n0 + r) * Ktot + k0 + cs * 8, &lB[buf][ch * 8]);
        }
    };

    const int nk = Kc >> 6;
    stage(0, kb);
    __syncthreads();
    int cur = 0;
    for (int t = 0; t < nk; ++t) {
        if (t + 1 < nk) stage(cur ^ 1, kb + ((t + 1) << 6));
        #pragma unroll
        for (int ks = 0; ks < 2; ++ks) {
            bf16x8 af[FM], bfv[FN];
            #pragma unroll
            for (int fm = 0; fm < FM; ++fm) {
                int row = wrow + fm * 16 + l16;
                int by = row * 128 + ((ks * 64 + lq * 16) ^ ((row & 7) << 4));
                af[fm] = *(const bf16x8*)((const char*)&lA[cur][0] + by);
            }
            #pragma unroll
            for (int fn = 0; fn < FN; ++fn) {
                int row = wcol + fn * 16 + l16;
                int by = row * 128 + ((ks * 64 + lq * 16) ^ ((row & 7) << 4));
                bfv[fn] = *(const bf16x8*)((const char*)&lB[cur][0] + by);
            }
            #pragma unroll
            for (int fm = 0; fm < FM; ++fm)
                #pragma unroll
                for (int fn = 0; fn < FN; ++fn)
                    acc[fm][fn] = __builtin_amdgcn_mfma_f32_16x16x32_bf16(af[fm], bfv[fn], acc[fm][fn], 0, 0, 0);
        }
        __syncthreads();
        cur ^= 1;
    }

    unsigned short* Pz = P + (size_t)bz * M * N;
    #pragma unroll
    for (int fm = 0; fm < FM; ++fm)
        #pragma unroll
        for (int fn = 0; fn < FN; ++fn) {
            int col = n0 + wcol + fn * 16 + l16;
            #pragma unroll
            for (int i = 0; i < 4; ++i) {
                int row = m0 + wrow + fm * 16 + 4 * lq + i;
                Pz[(size_t)row * N + col] = f2bf(acc[fm][fn][i]);
            }
        }
}

// ---------- split-K reduce (bf16 partials, vectorized) + bias + residual + LN ----------
template<int NP>
__global__ __launch_bounds__(256) void redsum_ln_k(const unsigned short* __restrict__ P,
                                                   const float* __restrict__ bias,
                                                   const float* __restrict__ res,
                                                   float* __restrict__ outf,
                                                   const float* __restrict__ g,
                                                   const float* __restrict__ b,
                                                   unsigned short* __restrict__ obf) {
    const size_t MN = (size_t)2048 * 768;
    int r = blockIdx.x, tid = threadIdx.x;
    int col = tid * 4;
    size_t idx = (size_t)r * 768 + col;
    float v0 = 0.f, v1 = 0.f, v2 = 0.f, v3 = 0.f;
    if (tid < 192) {
        float4 a4 = *(const float4*)(res + idx);
        float4 b4 = *(const float4*)(bias + col);
        v0 = a4.x + b4.x; v1 = a4.y + b4.y; v2 = a4.z + b4.z; v3 = a4.w + b4.w;
        #pragma unroll
        for (int pz = 0; pz < NP; ++pz) {
            ushort4 p4 = *(const ushort4*)(P + (size_t)pz * MN + idx);
            v0 += bf2f(p4.x); v1 += bf2f(p4.y); v2 += bf2f(p4.z); v3 += bf2f(p4.w);
        }
        float4 o4; o4.x = v0; o4.y = v1; o4.z = v2; o4.w = v3;
        *(float4*)(outf + idx) = o4;
    }
    if (!g) return;                      // block-uniform
    __shared__ float red[4];
    float s = v0 + v1 + v2 + v3;
    #pragma unroll
    for (int off = 32; off > 0; off >>= 1) s += __shfl_down(s, off);
    if ((tid & 63) == 0) red[tid >> 6] = s;
    __syncthreads();
    float mean = (red[0] + red[1] + red[2] + red[3]) * (1.0f / 768.0f);
    float d0 = v0 - mean, d1 = v1 - mean, d2 = v2 - mean, d3 = v3 - mean;
    float q = (tid < 192) ? (d0 * d0 + d1 * d1 + d2 * d2 + d3 * d3) : 0.f;
    __syncthreads();
    #pragma unroll
    for (int off = 32; off > 0; off >>= 1) q += __shfl_down(q, off);
    if ((tid & 63) == 0) red[tid >> 6] = q;
    __syncthreads();
    float var = (red[0] + red[1] + red[2] + red[3]) * (1.0f / 768.0f);
    float rs = rsqrtf(var + 1e-5f);
    if (tid < 192) {
        float4 g4 = *(const float4*)(g + col);
        float4 bb4 = *(const float4*)(b + col);
        ushort4 y4;
        y4.x = f2bf(d0 * rs * g4.x + bb4.x);
        y4.y = f2bf(d1 * rs * g4.y + bb4.y);
        y4.z = f2bf(d2 * rs * g4.z + bb4.z);
        y4.w = f2bf(d3 * rs * g4.w + bb4.w);
        *(ushort4*)(obf + idx) = y4;
    }
}

// ---------- launch ----------
extern "C" void kernel_launch(void* const* d_in, const int* in_sizes, int n_in,
                              void* d_out, int out_size, void* d_ws, size_t ws_size,
                              hipStream_t stream) {
    const float* filaments = (const float*)d_in[0];
    const float* mask      = (const float*)d_in[1];
    const float* ln_p1_g   = (const float*)d_in[2];
    const float* ln_p1_b   = (const float*)d_in[3];
    const float* W_patch   = (const float*)d_in[4];
    const float* b_patch   = (const float*)d_in[5];
    const float* ln_p2_g   = (const float*)d_in[6];
    const float* ln_p2_b   = (const float*)d_in[7];
    const float* peg_w     = (const float*)d_in[8];
    const float* peg_b     = (const float*)d_in[9];
    const float* cls_token = (const float*)d_in[10];
    const float* ln_a_g    = (const float*)d_in[11];
    const float* ln_a_b    = (const float*)d_in[12];
    const float* W_qkv     = (const float*)d_in[13];
    const float* W_o       = (const float*)d_in[14];
    const float* b_o       = (const float*)d_in[15];
    const float* inv_freq  = (const float*)d_in[16];
    const float* ln_f_g    = (const float*)d_in[17];
    const float* ln_f_b    = (const float*)d_in[18];
    const float* W1        = (const float*)d_in[19];
    const float* b1        = (const float*)d_in[20];
    const float* W2        = (const float*)d_in[21];
    const float* b2        = (const float*)d_in[22];

    // ---- workspace layout (~104 MB of ~400 MB) ----
    char* p = (char*)d_ws;
    float* xa            = (float*)p;          p += 2048 * 768 * 4;
    float* xb            = (float*)p;          p += 2048 * 768 * 4;
    unsigned short* h_bf = (unsigned short*)p; p += 2048 * 768 * 2;
    unsigned short* qkv  = (unsigned short*)p; p += 2048 * 3072 * 2;   // qkv / m_bf / patch-tmp overlay
    unsigned short* Pbuf = (unsigned short*)p; p += (size_t)4 * 2048 * 768 * 2;
    unsigned short* w1t  = (unsigned short*)p; p += (size_t)6 * 3072 * 768 * 2;
    unsigned short* w2t  = (unsigned short*)p; p += (size_t)6 * 3072 * 768 * 2;
    unsigned short* wqt  = (unsigned short*)p; p += 2304 * 768 * 2;
    unsigned short* wot  = (unsigned short*)p; p += 768 * 768 * 2;
    unsigned short* wpt  = (unsigned short*)p; p += 768 * 768 * 2;
    float* cosT          = (float*)p;          p += 16384 * 4;
    float* sinT          = (float*)p;          p += 16384 * 4;
    unsigned char* flags = (unsigned char*)p;  p += 8192;
    unsigned short* m_bf = qkv;
    float* tmp = (float*)qkv;                  // patch GEMM f32 out
    float* out = (float*)d_out;

    // ---- one-time precomputes ----
    mask_flags_k<<<6144, 256, 0, stream>>>(mask, flags);
    cossin_k<<<64, 256, 0, stream>>>(inv_freq, cosT, sinT);
    wt_cast_k<<<dim3(12, 12), 256, 0, stream>>>(W_patch, wpt, 768, 768);
    wt_cast_k<<<dim3(36, 12), 256, 0, stream>>>(W_qkv,  wqt, 768, 2304);
    wt_cast_k<<<dim3(12, 12), 256, 0, stream>>>(W_o,    wot, 768, 768);
    wt_cast_k<<<dim3(48, 12, 6), 256, 0, stream>>>(W1, w1t, 768, 3072);
    wt_cast_k<<<dim3(12, 48, 6), 256, 0, stream>>>(W2, w2t, 3072, 768);

    // ---- patch embed ----
    ln768_bf_k<<<2048, 256, 0, stream>>>(filaments, ln_p1_g, ln_p1_b, h_bf, 2046);
    gemm64_k<64, false, false, false><<<dim3(12, 32), 256, 0, stream>>>(h_bf, wpt, b_patch, nullptr, tmp,
                                                                        nullptr, nullptr, 2046, 768, 768);
    ln768_k<<<2046, 256, 0, stream>>>(tmp, ln_p2_g, ln_p2_b, xa, 1);
    cls_k<<<2, 256, 0, stream>>>(cls_token, xa);
    peg_ln_k<<<2048, 256, 0, stream>>>(xa, peg_w, peg_b, xb, ln_a_g, ln_a_b, h_bf);

    float* cur = xb;
    float* nxt = xa;
    for (int i = 0; i < 6; ++i) {
        // qkv projection with fused RoPE (h_bf holds ln_a(x)); 64x128 tile
        gemm64_k<128, false, true, true><<<dim3(18, 32), 256, 0, stream>>>(h_bf, wqt, nullptr, nullptr, qkv,
                                                                           cosT, sinT, 2048, 2304, 768);
        attn_mfma_k<<<dim3(16, 24), 256, 0, stream>>>(qkv, mask, flags, h_bf);
        // o-proj: split-K x4 at 64x128 tile (768 blocks = 3/CU) + fused reduce + ln_f
        gemm64_splitk_k<128><<<dim3(6, 32, 4), 256, 0, stream>>>(h_bf, wot, Pbuf, 2048, 768, 768, 192);
        redsum_ln_k<4><<<2048, 256, 0, stream>>>(Pbuf, b_o, cur, nxt,
                                                 ln_f_g + i * 768, ln_f_b + i * 768, h_bf);
        // MLP; mlp1 at 64x128 tile
        gemm64_k<128, true, true, false><<<dim3(24, 32), 256, 0, stream>>>(h_bf, w1t + (size_t)i * 3072 * 768, b1 + i * 3072,
                                                                           nullptr, m_bf, nullptr, nullptr, 2048, 3072, 768);
        // mlp2: split-K x4 at 64x128 tile (768 blocks = 3/CU)
        gemm64_splitk_k<128><<<dim3(6, 32, 4), 256, 0, stream>>>(m_bf, w2t + (size_t)i * 768 * 3072, Pbuf, 2048, 768, 3072, 768);
        redsum_ln_k<4><<<2048, 256, 0, stream>>>(Pbuf, b2 + i * 768, nxt, (i == 5) ? out : cur,
                                                 (i < 5) ? (ln_a_g + (i + 1) * 768) : nullptr,
                                                 (i < 5) ? (ln_a_b + (i + 1) * 768) : nullptr, h_bf);
    }
}